// Round 9
// baseline (433.088 us; speedup 1.0000x reference)
//
#include <hip/hip_runtime.h>
#include <hip/hip_bf16.h>

typedef __attribute__((ext_vector_type(8))) short short8;
typedef __attribute__((ext_vector_type(4))) float f32x4;

#define N_NODES 16384
#define FEAT 128
#define KSPLIT 2
#define NT2 64              // K-tiles of 128 per half (16384 / 128 / 2)

__device__ __forceinline__ short f2bf(float x) {
  union { float f; unsigned u; } v;
  v.f = x;
  unsigned r = v.u + 0x7fffu + ((v.u >> 16) & 1u);  // RNE; inputs finite
  return (short)(r >> 16);
}

// ---------- Kernel 1: dinv[i] = rsqrt(1 + sum_j adj[i][j]) ----------
__global__ __launch_bounds__(256) void rowsum_kernel(
    const float* __restrict__ adj, float* __restrict__ dinv)
{
  const int row = blockIdx.x;
  const float4* p4 = (const float4*)(adj + (size_t)row * N_NODES);
  float s = 0.f;
  #pragma unroll 4
  for (int i = threadIdx.x; i < N_NODES / 4; i += 256) {
    float4 v = p4[i];
    s += (v.x + v.y) + (v.z + v.w);
  }
  #pragma unroll
  for (int off = 32; off > 0; off >>= 1) s += __shfl_down(s, off, 64);
  __shared__ float part[4];
  if ((threadIdx.x & 63) == 0) part[threadIdx.x >> 6] = s;
  __syncthreads();
  if (threadIdx.x == 0) {
    float tot = (part[0] + part[1]) + (part[2] + part[3]) + 1.0f;
    dinv[row] = rsqrtf(tot);
  }
}

// ---------- Kernel 2: Ypack[(k>>3)*1024 + f*8 + (k&7)] = bf16(d_k * (X@W)[k][f]) ----------
__global__ __launch_bounds__(256) void xw_kernel(
    const float* __restrict__ X, const float* __restrict__ W,
    const float* __restrict__ dinv,
    __hip_bfloat16* __restrict__ Ypack)
{
  __shared__ __align__(16) float Ws[64][128];
  __shared__ __align__(16) float Xs[32][128];
  __shared__ __align__(16) short Ts[128][40];
  const int tid = threadIdx.x;
  const int row0 = blockIdx.x << 5;

  {
    const float4* Xg = (const float4*)(X + ((size_t)row0 << 7));
    float4* Xl = (float4*)&Xs[0][0];
    #pragma unroll
    for (int i = 0; i < 4; ++i) Xl[tid + (i << 8)] = Xg[tid + (i << 8)];
  }
  const int f  = tid & 127;
  const int rr = tid >> 7;
  float acc[16];
  #pragma unroll
  for (int k = 0; k < 16; ++k) acc[k] = 0.f;

  for (int cc = 0; cc < 2; ++cc) {
    __syncthreads();
    {
      const float4* Wg = (const float4*)(W + ((size_t)cc << 13));
      float4* Wl = (float4*)&Ws[0][0];
      #pragma unroll
      for (int i = 0; i < 8; ++i) Wl[tid + (i << 8)] = Wg[tid + (i << 8)];
    }
    __syncthreads();
    for (int c4 = 0; c4 < 16; ++c4) {
      const int cl = c4 << 2;
      const float w0 = Ws[cl + 0][f];
      const float w1 = Ws[cl + 1][f];
      const float w2 = Ws[cl + 2][f];
      const float w3 = Ws[cl + 3][f];
      const int cg = (cc << 6) + cl;
      #pragma unroll
      for (int k = 0; k < 16; ++k) {
        const float4 x = *(const float4*)&Xs[rr + (k << 1)][cg];
        acc[k] += x.x * w0 + x.y * w1 + x.z * w2 + x.w * w3;
      }
    }
  }
  #pragma unroll
  for (int k = 0; k < 16; ++k) {
    const int r = rr + (k << 1);
    const float dv = dinv[row0 + r];
    Ts[f][r] = f2bf(acc[k] * dv);
  }
  __syncthreads();
  {
    const int f2 = tid >> 1;
    const int h  = (tid & 1) << 4;
    const short8 v0 = *(const short8*)&Ts[f2][h];
    const short8 v1 = *(const short8*)&Ts[f2][h + 8];
    short* o = (short*)Ypack;
    *(short8*)(o + (size_t)(row0 + h) * FEAT + (f2 << 3))     = v0;
    *(short8*)(o + (size_t)(row0 + h + 8) * FEAT + (f2 << 3)) = v1;
  }
}

// ---------- Kernel 3: pws[s][row][f] = (A_hat[:, half s] @ Y-half)[row][f] ----------
// BM=128, BK=128: each A-row visit is 512 B contiguous (DRAM page locality —
// the one axis untested). 1024 thr (16 waves), grid 256, 128 KiB LDS
// (1 block/CU). Y: one-glds-pair per tile, double-buffered. A: fp32 reg
// prefetch (issued a full iter ahead; LOADA before GLDSY so the staging wait
// is counted vmcnt(2)). Diag +I folded at convert. XCD-swizzled blocks.
__global__ __launch_bounds__(1024, 4) void spmm_kernel(
    const float* __restrict__ A,
    const __hip_bfloat16* __restrict__ Ypack,
    float* __restrict__ pws)
{
  __shared__ __align__(16) short As[2][16384];   // [g 0..15][row 0..127][j 0..7], 32 KiB/buf
  __shared__ __align__(16) short Bs[2][16384];   // [g 0..15][f 0..127][j 0..7], 32 KiB/buf

  const int tid = threadIdx.x;
  const int rb  = blockIdx.x;
  const int lb  = ((rb & 7) << 5) | (rb >> 3);   // XCD x -> logical [x*32, x*32+32)
  const int mt  = lb & 127;
  const int s   = lb >> 7;
  const int row0 = mt << 7;

  const int ar = tid >> 3;           // A row 0..127
  const int kg = tid & 7;            // 16-float k-group
  const float* Ag = A + (size_t)(row0 + ar) * N_NODES + (s << 13) + (kg << 4);
  const short* Yg = (const short*)Ypack + ((size_t)s << 20) + (tid << 3);

  const int wid  = tid >> 6;
  const int wm   = wid >> 1;         // 0..7: 16-row M-subtile
  const int wf   = wid & 1;          // 0..1: 64-col F-half
  const int lane = tid & 63;
  const int lm   = lane & 15;
  const int lkg  = lane >> 4;
  const int myrow = (wm << 4) + lm;  // 0..127

  f32x4 acc[4];
  #pragma unroll
  for (int c = 0; c < 4; ++c) acc[c] = (f32x4){0.f, 0.f, 0.f, 0.f};

  float4 pa0, pa1, pa2, pa3;

#define LOADA(T)                                                               \
  {                                                                            \
    const float* ap = Ag + ((size_t)(T) << 7);                                 \
    pa0 = *(const float4*)(ap);                                                \
    pa1 = *(const float4*)(ap + 4);                                            \
    pa2 = *(const float4*)(ap + 8);                                            \
    pa3 = *(const float4*)(ap + 12);                                           \
  }

#define GLDSY(T, P)                                                            \
  {                                                                            \
    const short* ys_ = Yg + ((size_t)(T) << 14);                               \
    __builtin_amdgcn_global_load_lds(                                          \
        (const __attribute__((address_space(1))) void*)ys_,                    \
        (__attribute__((address_space(3))) void*)&Bs[P][wid << 9], 16, 0, 0);  \
    __builtin_amdgcn_global_load_lds(                                          \
        (const __attribute__((address_space(1))) void*)(ys_ + 8192),           \
        (__attribute__((address_space(3))) void*)&Bs[P][8192 + (wid << 9)],    \
        16, 0, 0);                                                             \
  }

#define STORA(T, P)                                                            \
  {                                                                            \
    const int j = (row0 + ar) - (((s << 6) + (T)) << 7) - (kg << 4);           \
    if (j >= 0 && j < 16) {  /* A_hat = A + I */                               \
      pa0.x += (j == 0)  ? 1.f : 0.f;  pa0.y += (j == 1)  ? 1.f : 0.f;         \
      pa0.z += (j == 2)  ? 1.f : 0.f;  pa0.w += (j == 3)  ? 1.f : 0.f;         \
      pa1.x += (j == 4)  ? 1.f : 0.f;  pa1.y += (j == 5)  ? 1.f : 0.f;         \
      pa1.z += (j == 6)  ? 1.f : 0.f;  pa1.w += (j == 7)  ? 1.f : 0.f;         \
      pa2.x += (j == 8)  ? 1.f : 0.f;  pa2.y += (j == 9)  ? 1.f : 0.f;         \
      pa2.z += (j == 10) ? 1.f : 0.f;  pa2.w += (j == 11) ? 1.f : 0.f;         \
      pa3.x += (j == 12) ? 1.f : 0.f;  pa3.y += (j == 13) ? 1.f : 0.f;         \
      pa3.z += (j == 14) ? 1.f : 0.f;  pa3.w += (j == 15) ? 1.f : 0.f;         \
    }                                                                          \
    short8 av0, av1;                                                           \
    av0[0] = f2bf(pa0.x); av0[1] = f2bf(pa0.y); av0[2] = f2bf(pa0.z);          \
    av0[3] = f2bf(pa0.w); av0[4] = f2bf(pa1.x); av0[5] = f2bf(pa1.y);          \
    av0[6] = f2bf(pa1.z); av0[7] = f2bf(pa1.w);                                \
    av1[0] = f2bf(pa2.x); av1[1] = f2bf(pa2.y); av1[2] = f2bf(pa2.z);          \
    av1[3] = f2bf(pa2.w); av1[4] = f2bf(pa3.x); av1[5] = f2bf(pa3.y);          \
    av1[6] = f2bf(pa3.z); av1[7] = f2bf(pa3.w);                                \
    *(short8*)&As[P][((kg << 1) << 10) + (ar << 3)]       = av0;               \
    *(short8*)&As[P][(((kg << 1) + 1) << 10) + (ar << 3)] = av1;               \
  }

#define COMP(P)                                                                \
  {                                                                            \
    _Pragma("unroll")                                                          \
    for (int ks = 0; ks < 4; ++ks) {                                           \
      const short8 af =                                                        \
          *(const short8*)&As[P][(((ks << 2) + lkg) << 10) + (myrow << 3)];    \
      _Pragma("unroll")                                                        \
      for (int c = 0; c < 4; ++c) {                                            \
        acc[c] = __builtin_amdgcn_mfma_f32_16x16x32_bf16(af,                   \
            *(const short8*)&Bs[P][(((ks << 2) + lkg) << 10) +                 \
                                   (((wf << 6) + (c << 4) + lm) << 3)],        \
            acc[c], 0, 0, 0);                                                  \
      }                                                                        \
    }                                                                          \
  }

  // prologue: stage tile 0
  LOADA(0)
  GLDSY(0, 0)
  STORA(0, 0)                                       // waits A(0) regs only
  asm volatile("s_waitcnt vmcnt(0)" ::: "memory");  // Y(0) landed
  asm volatile("s_waitcnt lgkmcnt(0)" ::: "memory");
  __builtin_amdgcn_s_barrier();

  for (int t = 0; t < NT2; ++t) {
    const int p = t & 1;
    if (t + 1 < NT2) { LOADA(t + 1) GLDSY(t + 1, p ^ 1) }   // A before Y: counted wait
    __builtin_amdgcn_s_setprio(1);
    COMP(p)
    __builtin_amdgcn_s_setprio(0);
    if (t + 1 < NT2) STORA(t + 1, p ^ 1)            // implicit vmcnt(2): Y stays in flight
    asm volatile("s_waitcnt vmcnt(0)" ::: "memory"); // Y(t+1): issued a full iter ago
    asm volatile("s_waitcnt lgkmcnt(0)" ::: "memory");
    __builtin_amdgcn_s_barrier();
  }

  // epilogue: fp32 partial
  float* pp = pws + ((size_t)(s * N_NODES + row0)) * FEAT;
  const int lr = (lane >> 4) << 2;
  #pragma unroll
  for (int c = 0; c < 4; ++c) {
    const int col = (wf << 6) + (c << 4) + lm;
    #pragma unroll
    for (int r = 0; r < 4; ++r) {
      pp[(size_t)((wm << 4) + lr + r) * FEAT + col] = acc[c][r];
    }
  }
#undef LOADA
#undef GLDSY
#undef STORA
#undef COMP
}

// ---------- Kernel 4: out = relu(dinv[row] * (p0 + p1) + bias) ----------
__global__ __launch_bounds__(256) void reduce_kernel(
    const float* __restrict__ pws, const float* __restrict__ dinv,
    const float* __restrict__ bias, float* __restrict__ out)
{
  const int idx4 = blockIdx.x * 256 + threadIdx.x;
  const int row  = idx4 >> 5;
  const int f4   = idx4 & 31;
  const float4 p0 = ((const float4*)pws)[idx4];
  const float4 p1 = ((const float4*)pws)[idx4 + (N_NODES * FEAT / 4)];
  const float4 bv = ((const float4*)bias)[f4];
  const float  d  = dinv[row];
  float4 v;
  v.x = d * (p0.x + p1.x) + bv.x;
  v.y = d * (p0.y + p1.y) + bv.y;
  v.z = d * (p0.z + p1.z) + bv.z;
  v.w = d * (p0.w + p1.w) + bv.w;
  v.x = v.x > 0.f ? v.x : 0.f;
  v.y = v.y > 0.f ? v.y : 0.f;
  v.z = v.z > 0.f ? v.z : 0.f;
  v.w = v.w > 0.f ? v.w : 0.f;
  ((float4*)out)[idx4] = v;
}

extern "C" void kernel_launch(void* const* d_in, const int* in_sizes, int n_in,
                              void* d_out, int out_size, void* d_ws, size_t ws_size,
                              hipStream_t stream) {
  const float* X   = (const float*)d_in[0];
  const float* adj = (const float*)d_in[1];
  const float* W   = (const float*)d_in[2];
  const float* b   = (const float*)d_in[3];
  float* out = (float*)d_out;

  float* dinv           = (float*)d_ws;                                   // 64 KiB
  __hip_bfloat16* Ypack = (__hip_bfloat16*)((char*)d_ws + (1 << 16));     // 4 MiB
  float* pws            = (float*)((char*)d_ws + (1 << 16) + (1 << 22));  // 16 MiB

  rowsum_kernel<<<N_NODES, 256, 0, stream>>>(adj, dinv);
  xw_kernel<<<N_NODES / 32, 256, 0, stream>>>(X, W, dinv, Ypack);
  spmm_kernel<<<128 * KSPLIT, 1024, 0, stream>>>(adj, Ypack, pws);
  reduce_kernel<<<N_NODES * FEAT / 4 / 256, 256, 0, stream>>>(pws, dinv, b, out);
}

// Round 11
// 413.218 us; speedup vs baseline: 1.0481x; 1.0481x over previous
//
#include <hip/hip_runtime.h>
#include <hip/hip_bf16.h>

typedef __attribute__((ext_vector_type(8))) short short8;
typedef __attribute__((ext_vector_type(4))) float f32x4;

#define N_NODES 16384
#define FEAT 128
#define NTILES 256          // K-tiles of 64 overall
#define KSPLIT 2
#define NT2 (NTILES / KSPLIT)

__device__ __forceinline__ short f2bf(float x) {
  union { float f; unsigned u; } v;
  v.f = x;
  unsigned r = v.u + 0x7fffu + ((v.u >> 16) & 1u);  // RNE; inputs finite
  return (short)(r >> 16);
}

// ---------- Kernel 1 (fused): blocks [0,16384): dinv[i]=rsqrt(1+rowsum(adj,i))
//            blocks [16384,16896): Upack = XW (unscaled; d_j folded into spmm)
// xw part no longer depends on dinv -> its traffic hides under rowsum's.
__global__ __launch_bounds__(256) void pre_kernel(
    const float* __restrict__ adj, const float* __restrict__ X,
    const float* __restrict__ W, float* __restrict__ dinv,
    __hip_bfloat16* __restrict__ Upack)
{
  __shared__ __align__(16) float Ws[64][128];
  __shared__ __align__(16) float Xs[32][128];
  __shared__ __align__(16) short Ts[128][40];
  __shared__ float part[4];
  const int tid = threadIdx.x;

  if (blockIdx.x < N_NODES) {
    // ---- rowsum path ----
    const int row = blockIdx.x;
    const float4* p4 = (const float4*)(adj + (size_t)row * N_NODES);
    float s = 0.f;
    #pragma unroll 4
    for (int i = tid; i < N_NODES / 4; i += 256) {
      float4 v = p4[i];
      s += (v.x + v.y) + (v.z + v.w);
    }
    #pragma unroll
    for (int off = 32; off > 0; off >>= 1) s += __shfl_down(s, off, 64);
    if ((tid & 63) == 0) part[tid >> 6] = s;
    __syncthreads();
    if (tid == 0) {
      float tot = (part[0] + part[1]) + (part[2] + part[3]) + 1.0f;
      dinv[row] = rsqrtf(tot);
    }
    return;
  }

  // ---- U = X@W path (unscaled) ----
  const int row0 = (blockIdx.x - N_NODES) << 5;
  {
    const float4* Xg = (const float4*)(X + ((size_t)row0 << 7));
    float4* Xl = (float4*)&Xs[0][0];
    #pragma unroll
    for (int i = 0; i < 4; ++i) Xl[tid + (i << 8)] = Xg[tid + (i << 8)];
  }
  const int f  = tid & 127;
  const int rr = tid >> 7;
  float acc[16];
  #pragma unroll
  for (int k = 0; k < 16; ++k) acc[k] = 0.f;

  for (int cc = 0; cc < 2; ++cc) {
    __syncthreads();
    {
      const float4* Wg = (const float4*)(W + ((size_t)cc << 13));
      float4* Wl = (float4*)&Ws[0][0];
      #pragma unroll
      for (int i = 0; i < 8; ++i) Wl[tid + (i << 8)] = Wg[tid + (i << 8)];
    }
    __syncthreads();
    for (int c4 = 0; c4 < 16; ++c4) {
      const int cl = c4 << 2;
      const float w0 = Ws[cl + 0][f];
      const float w1 = Ws[cl + 1][f];
      const float w2 = Ws[cl + 2][f];
      const float w3 = Ws[cl + 3][f];
      const int cg = (cc << 6) + cl;
      #pragma unroll
      for (int k = 0; k < 16; ++k) {
        const float4 x = *(const float4*)&Xs[rr + (k << 1)][cg];
        acc[k] += x.x * w0 + x.y * w1 + x.z * w2 + x.w * w3;
      }
    }
  }
  #pragma unroll
  for (int k = 0; k < 16; ++k) {
    const int r = rr + (k << 1);
    Ts[f][r] = f2bf(acc[k]);
  }
  __syncthreads();
  {
    const int f2 = tid >> 1;
    const int h  = (tid & 1) << 4;
    const short8 v0 = *(const short8*)&Ts[f2][h];
    const short8 v1 = *(const short8*)&Ts[f2][h + 8];
    short* o = (short*)Upack;
    *(short8*)(o + (size_t)(row0 + h) * FEAT + (f2 << 3))     = v0;
    *(short8*)(o + (size_t)(row0 + h + 8) * FEAT + (f2 << 3)) = v1;
  }
}

// ---------- Kernel 2: pws[s][row][f] = ((A+I)D^-1/2 [:, half s] @ U-half) ----------
// r5 structure (best, 409 us): split-K=2, 2 blocks/CU, raw barrier + counted
// vmcnt, 2-deep reg prefetch, setprio. d_j column scaling folded into A
// staging (dinv L1-resident). FIX vs r10: Yg stride tid<<4 (16 shorts/thread
// reg staging), not the glds-style tid<<3 that mis-staged half of every Y tile.
__global__ __launch_bounds__(512, 4) void spmm_kernel(
    const float* __restrict__ A,
    const __hip_bfloat16* __restrict__ Upack,
    const float* __restrict__ dinv,
    float* __restrict__ pws)
{
  __shared__ __align__(16) short As[2][4096];   // [kgrp][row][8], 8 KiB/buf
  __shared__ __align__(16) short Bs[2][8192];   // [kgrp][f][8], 16 KiB/buf

  const int tid = threadIdx.x;
  const int bid = blockIdx.x;
  const int mt  = bid & 255;         // M-tile
  const int s   = bid >> 8;          // K-half
  const int row0 = mt << 6;

  const int ar  = tid >> 3;          // A row 0..63
  const int akg = tid & 7;           // A k-group (8 floats)
  const float* Ag = A + (size_t)(row0 + ar) * N_NODES + (s * NT2 << 6) + (akg << 3);
  const short* Yg = (const short*)Upack + ((size_t)(s * NT2) << 13) + (tid << 4);

  const int wid  = tid >> 6;
  const int wm   = wid >> 1;
  const int wf   = wid & 1;
  const int lane = tid & 63;
  const int lm   = lane & 15;
  const int lkg  = lane >> 4;
  const int myrow = (wm << 4) + lm;

  f32x4 acc[4];
  #pragma unroll
  for (int c = 0; c < 4; ++c) acc[c] = (f32x4){0.f, 0.f, 0.f, 0.f};

  float4 a0A, a1A, a0B, a1B, d0A, d1A, d0B, d1B;
  short8 y0A, y1A, y0B, y1B;

#define LOADT(T, A0_, A1_, D0_, D1_, Y0_, Y1_)                                 \
  {                                                                            \
    const float* ap = Ag + ((size_t)(T) << 6);                                 \
    A0_ = *(const float4*)(ap);                                                \
    A1_ = *(const float4*)(ap + 4);                                            \
    const float* dp = dinv + ((s * NT2 + (T)) << 6) + (akg << 3);              \
    D0_ = *(const float4*)(dp);                                                \
    D1_ = *(const float4*)(dp + 4);                                            \
    const short* yp = Yg + ((size_t)(T) << 13);                                \
    Y0_ = *(const short8*)(yp);                                                \
    Y1_ = *(const short8*)(yp + 8);                                            \
  }

#define STORET(T, P, A0_, A1_, D0_, D1_, Y0_, Y1_)                             \
  {                                                                            \
    if (s * NT2 + (T) == mt && (ar >> 3) == akg) {  /* A_hat = A + I */        \
      const int j = ar & 7;                                                    \
      A0_.x += (j == 0) ? 1.f : 0.f;  A0_.y += (j == 1) ? 1.f : 0.f;           \
      A0_.z += (j == 2) ? 1.f : 0.f;  A0_.w += (j == 3) ? 1.f : 0.f;           \
      A1_.x += (j == 4) ? 1.f : 0.f;  A1_.y += (j == 5) ? 1.f : 0.f;           \
      A1_.z += (j == 6) ? 1.f : 0.f;  A1_.w += (j == 7) ? 1.f : 0.f;           \
    }                                                                          \
    A0_.x *= D0_.x; A0_.y *= D0_.y; A0_.z *= D0_.z; A0_.w *= D0_.w;            \
    A1_.x *= D1_.x; A1_.y *= D1_.y; A1_.z *= D1_.z; A1_.w *= D1_.w;            \
    short8 av;                                                                 \
    av[0] = f2bf(A0_.x); av[1] = f2bf(A0_.y); av[2] = f2bf(A0_.z);             \
    av[3] = f2bf(A0_.w); av[4] = f2bf(A1_.x); av[5] = f2bf(A1_.y);             \
    av[6] = f2bf(A1_.z); av[7] = f2bf(A1_.w);                                  \
    *(short8*)&As[P][(akg << 9) + (ar << 3)] = av;                             \
    *(short8*)&Bs[P][tid << 4]       = Y0_;                                    \
    *(short8*)&Bs[P][(tid << 4) + 8] = Y1_;                                    \
  }

#define COMP(P)                                                                \
  {                                                                            \
    const short8 af0 = *(const short8*)&As[P][(lkg << 9) + (myrow << 3)];      \
    acc[0] = __builtin_amdgcn_mfma_f32_16x16x32_bf16(af0,                      \
        *(const short8*)&Bs[P][(lkg << 10) + (((wf << 6) + lm) << 3)], acc[0], 0, 0, 0); \
    acc[1] = __builtin_amdgcn_mfma_f32_16x16x32_bf16(af0,                      \
        *(const short8*)&Bs[P][(lkg << 10) + (((wf << 6) + 16 + lm) << 3)], acc[1], 0, 0, 0); \
    acc[2] = __builtin_amdgcn_mfma_f32_16x16x32_bf16(af0,                      \
        *(const short8*)&Bs[P][(lkg << 10) + (((wf << 6) + 32 + lm) << 3)], acc[2], 0, 0, 0); \
    acc[3] = __builtin_amdgcn_mfma_f32_16x16x32_bf16(af0,                      \
        *(const short8*)&Bs[P][(lkg << 10) + (((wf << 6) + 48 + lm) << 3)], acc[3], 0, 0, 0); \
    const short8 af1 = *(const short8*)&As[P][((4 + lkg) << 9) + (myrow << 3)]; \
    acc[0] = __builtin_amdgcn_mfma_f32_16x16x32_bf16(af1,                      \
        *(const short8*)&Bs[P][((4 + lkg) << 10) + (((wf << 6) + lm) << 3)], acc[0], 0, 0, 0); \
    acc[1] = __builtin_amdgcn_mfma_f32_16x16x32_bf16(af1,                      \
        *(const short8*)&Bs[P][((4 + lkg) << 10) + (((wf << 6) + 16 + lm) << 3)], acc[1], 0, 0, 0); \
    acc[2] = __builtin_amdgcn_mfma_f32_16x16x32_bf16(af1,                      \
        *(const short8*)&Bs[P][((4 + lkg) << 10) + (((wf << 6) + 32 + lm) << 3)], acc[2], 0, 0, 0); \
    acc[3] = __builtin_amdgcn_mfma_f32_16x16x32_bf16(af1,                      \
        *(const short8*)&Bs[P][((4 + lkg) << 10) + (((wf << 6) + 48 + lm) << 3)], acc[3], 0, 0, 0); \
  }

#define BAR()                                                                  \
  asm volatile("s_waitcnt lgkmcnt(0)" ::: "memory");                           \
  __builtin_amdgcn_s_barrier();

  // prologue: tiles 0,1 -> regs; stage tile 0
  LOADT(0, a0A, a1A, d0A, d1A, y0A, y1A)
  LOADT(1, a0B, a1B, d0B, d1B, y0B, y1B)
  STORET(0, 0, a0A, a1A, d0A, d1A, y0A, y1A)
  BAR()

  for (int t = 0; t < NT2; t += 2) {
    if (t + 2 < NT2) LOADT(t + 2, a0A, a1A, d0A, d1A, y0A, y1A)
    __builtin_amdgcn_s_setprio(1);
    COMP(0)
    __builtin_amdgcn_s_setprio(0);
    if (t + 1 < NT2) STORET(t + 1, 1, a0B, a1B, d0B, d1B, y0B, y1B)
    BAR()
    if (t + 3 < NT2) LOADT(t + 3, a0B, a1B, d0B, d1B, y0B, y1B)
    __builtin_amdgcn_s_setprio(1);
    COMP(1)
    __builtin_amdgcn_s_setprio(0);
    if (t + 2 < NT2) STORET(t + 2, 0, a0A, a1A, d0A, d1A, y0A, y1A)
    BAR()
  }

  // write fp32 partial
  float* pp = pws + ((size_t)(s * N_NODES + row0)) * FEAT;
  const int lr = (lane >> 4) << 2;
  #pragma unroll
  for (int c = 0; c < 4; ++c) {
    const int col = (wf << 6) + (c << 4) + lm;
    #pragma unroll
    for (int r = 0; r < 4; ++r) {
      pp[(size_t)((wm << 4) + lr + r) * FEAT + col] = acc[c][r];
    }
  }
#undef LOADT
#undef STORET
#undef COMP
#undef BAR
}

// ---------- Kernel 3: out = relu(dinv[row] * (p0 + p1) + bias) ----------
__global__ __launch_bounds__(256) void reduce_kernel(
    const float* __restrict__ pws, const float* __restrict__ dinv,
    const float* __restrict__ bias, float* __restrict__ out)
{
  const int idx4 = blockIdx.x * 256 + threadIdx.x;
  const int row  = idx4 >> 5;
  const int f4   = idx4 & 31;
  const float4 p0 = ((const float4*)pws)[idx4];
  const float4 p1 = ((const float4*)pws)[idx4 + (N_NODES * FEAT / 4)];
  const float4 bv = ((const float4*)bias)[f4];
  const float  d  = dinv[row];
  float4 v;
  v.x = d * (p0.x + p1.x) + bv.x;
  v.y = d * (p0.y + p1.y) + bv.y;
  v.z = d * (p0.z + p1.z) + bv.z;
  v.w = d * (p0.w + p1.w) + bv.w;
  v.x = v.x > 0.f ? v.x : 0.f;
  v.y = v.y > 0.f ? v.y : 0.f;
  v.z = v.z > 0.f ? v.z : 0.f;
  v.w = v.w > 0.f ? v.w : 0.f;
  ((float4*)out)[idx4] = v;
}

extern "C" void kernel_launch(void* const* d_in, const int* in_sizes, int n_in,
                              void* d_out, int out_size, void* d_ws, size_t ws_size,
                              hipStream_t stream) {
  const float* X   = (const float*)d_in[0];
  const float* adj = (const float*)d_in[1];
  const float* W   = (const float*)d_in[2];
  const float* b   = (const float*)d_in[3];
  float* out = (float*)d_out;

  float* dinv           = (float*)d_ws;                                   // 64 KiB
  __hip_bfloat16* Upack = (__hip_bfloat16*)((char*)d_ws + (1 << 16));     // 4 MiB
  float* pws            = (float*)((char*)d_ws + (1 << 16) + (1 << 22));  // 16 MiB

  pre_kernel<<<N_NODES + N_NODES / 32, 256, 0, stream>>>(adj, X, W, dinv, Upack);
  spmm_kernel<<<NTILES * KSPLIT, 512, 0, stream>>>(adj, Upack, dinv, pws);
  reduce_kernel<<<N_NODES * FEAT / 4 / 256, 256, 0, stream>>>(pws, dinv, b, out);
}